// Round 5
// baseline (516.016 us; speedup 1.0000x reference)
//
#include <hip/hip_runtime.h>

#define DEV __device__ __forceinline__
typedef unsigned short u16;
typedef __bf16 bf16x8 __attribute__((ext_vector_type(8)));
typedef float f32x4 __attribute__((ext_vector_type(4)));

DEV u16 f2bf(float f) {                      // RNE f32 -> bf16
  unsigned u = __float_as_uint(f);
  u += 0x7FFF + ((u >> 16) & 1);
  return (u16)(u >> 16);
}

// ---------------- geometry ----------------
// x    [64,3,125,125] fp32
// z1t  [64,63,64,32]  bf16 (w padded to 64, col63=0)   conv1 out
// z2   [64,64,32,32]  fp32                             conv2 out (MFMA)
// z3   [64,64,32,32]  fp32                             conv3 out
// e_t  [64,32,32,64]  bf16  pixel-major                VQ out
// h1t  [64,64,64,64]  bf16  pixel-major                convT1 out (MFMA)
// h2t  [64,128,128,32] bf16 pixel-major                convT2 out (MFMA)
// xr   [64,3,125,125] fp32
//
// MFMA 16x16x32 bf16: A[m=lane&15][k=(lane>>4)*8+j], D col=lane&15,
// row=(lane>>4)*4+reg. Both-parity waves: one wave's 16 A-rows (input
// pixels m+dx) produce 32 output columns (even via kw=1, odd via kw=0,2).

// ---------------- prep ----------------
// wc1p [cog4][ci3][tap9][8] fp32        conv1 weights
// wc3p [cog8][ci64][8] fp32             conv3 weights
// wt3n [kh2][kw2][ci32][4] fp32         convT3 weights (co padded to 4)
// c2   [512] fp32                       ||codebook||^2
// w2f  [tap9][nf4][lane64][8] bf16      conv2  B-frags (K=32=ci)
// wt1f [tap9][s2][nf4][lane64][8] bf16  convT1 B-frags (K=64, 2 kslices)
// wt2f [tap9][s2][nf2][lane64][8] bf16  convT2 B-frags
__global__ __launch_bounds__(256) void k_prep(
    const float* __restrict__ ew1, const float* __restrict__ ew2,
    const float* __restrict__ ew3, const float* __restrict__ dw1,
    const float* __restrict__ dw2, const float* __restrict__ dw3,
    const float* __restrict__ cb,
    float* __restrict__ wc1p, float* __restrict__ wc3p,
    float* __restrict__ wt3, float* __restrict__ c2,
    u16* __restrict__ w2f, u16* __restrict__ wt1f, u16* __restrict__ wt2f) {
  int i = blockIdx.x * 256 + threadIdx.x;
  if (i < 864) {
    int cl = i & 7; int t = i >> 3; int tap = t % 9; t /= 9; int ci = t % 3; int cog = t / 3;
    wc1p[i] = ew1[((cog * 8 + cl) * 3 + ci) * 9 + tap];
  } else if (i < 4960) {
    int j = i - 864; int cl = j & 7; int t = j >> 3; int ci = t & 63; int cog = t >> 6;
    wc3p[j] = ew3[(cog * 8 + cl) * 64 + ci];
  } else if (i < 5472) {
    int j = i - 4960;                       // [kh][kw][ci32][4]
    int co = j & 3; int ci = (j >> 2) & 31; int kw = (j >> 7) & 1; int kh = j >> 8;
    wt3[j] = (co < 3) ? dw3[((ci * 3 + co) * 2 + kh) * 2 + kw] : 0.f;
  } else if (i < 5984) {
    int k = i - 5472;
    const float4* c4 = (const float4*)(cb + (k << 6));
    float s = 0.f;
    #pragma unroll
    for (int q = 0; q < 16; ++q) { float4 v = c4[q]; s += v.x*v.x + v.y*v.y + v.z*v.z + v.w*v.w; }
    c2[k] = s;
  } else if (i < 24416) {
    int j = i - 5984;                       // [kt][nf][lane][8]
    int jj = j & 7; int lane = (j >> 3) & 63; int nf = (j >> 9) & 3; int kt = j >> 11;
    int kh = kt / 3, kw = kt % 3;
    int ci = ((lane >> 4) << 3) + jj; int co = (nf << 4) + (lane & 15);
    w2f[j] = f2bf(ew2[((co * 32 + ci) * 3 + kh) * 3 + kw]);
  } else if (i < 61280) {
    int j = i - 24416;                      // [kt][s][nf][lane][8]
    int jj = j & 7; int lane = (j >> 3) & 63; int nf = (j >> 9) & 3; int s = (j >> 11) & 1; int kt = j >> 12;
    int kh = kt / 3, kw = kt % 3;
    int ci = (s << 5) + ((lane >> 4) << 3) + jj; int co = (nf << 4) + (lane & 15);
    wt1f[j] = f2bf(dw1[((ci * 64 + co) * 3 + kh) * 3 + kw]);
  } else if (i < 79712) {
    int j = i - 61280;                      // [kt][s][nf][lane][8]
    int jj = j & 7; int lane = (j >> 3) & 63; int nf = (j >> 9) & 1; int s = (j >> 10) & 1; int kt = j >> 11;
    int kh = kt / 3, kw = kt % 3;
    int ci = (s << 5) + ((lane >> 4) << 3) + jj; int co = (nf << 4) + (lane & 15);
    wt2f[j] = f2bf(dw2[((ci * 32 + co) * 3 + kh) * 3 + kw]);
  }
}

// ---------------- conv1: fp32 VALU, 8co x 4ow/thread, out z1t bf16 ----------------
__global__ __launch_bounds__(256, 4) void k_conv1(
    const float* __restrict__ x, const float* __restrict__ wp,
    const float* __restrict__ bias, u16* __restrict__ z1t) {
  int t = threadIdx.x;
  int bid = blockIdx.x;              // 1024 = 64b x 4cog x 4ohT
  int ohT = bid & 3; int cog = (bid >> 2) & 3; int b = bid >> 4;
  const float* wcg = wp + cog * 216;
  int tx = t & 15, ty = t >> 4;
  int oh = ohT * 16 + ty; int ow0 = tx * 4; int co0 = cog * 8;
  bool ohok = oh < 63;
  float acc[8][4];
  #pragma unroll
  for (int c = 0; c < 8; ++c) {
    float bv = bias[co0 + c];
    #pragma unroll
    for (int s = 0; s < 4; ++s) acc[c][s] = bv;
  }
  int ih0 = 2 * oh - 1, iw0 = 8 * tx - 1;
  #pragma unroll
  for (int ci = 0; ci < 3; ++ci) {
    #pragma unroll
    for (int kh = 0; kh < 3; ++kh) {
      int ih = ih0 + kh;
      bool hok = ohok && ((unsigned)ih < 125u);
      const float* rp = x + (b * 3 + ci) * 15625 + ih * 125;
      float v[9];
      #pragma unroll
      for (int j = 0; j < 9; ++j) {
        int iw = iw0 + j;
        v[j] = (hok && ((unsigned)iw < 125u)) ? rp[iw] : 0.f;
      }
      #pragma unroll
      for (int kw = 0; kw < 3; ++kw) {
        const float* wq = wcg + (ci * 9 + kh * 3 + kw) * 8;
        float4 wa = *(const float4*)wq;
        float4 wb = *(const float4*)(wq + 4);
        float w8[8] = {wa.x, wa.y, wa.z, wa.w, wb.x, wb.y, wb.z, wb.w};
        #pragma unroll
        for (int s = 0; s < 4; ++s) {
          float in = v[2 * s + kw];
          #pragma unroll
          for (int c = 0; c < 8; ++c) acc[c][s] = fmaf(in, w8[c], acc[c][s]);
        }
      }
    }
  }
  if (ohok) {
    u16* op = z1t + ((b * 63 + oh) * 64 + ow0) * 32 + co0;
    #pragma unroll
    for (int s = 0; s < 4; ++s) {
      bool wok = (ow0 + s) < 63;
      unsigned p0 = 0, p1 = 0, p2 = 0, p3 = 0;
      if (wok) {
        p0 = f2bf(fmaxf(acc[0][s], 0.f)) | ((unsigned)f2bf(fmaxf(acc[1][s], 0.f)) << 16);
        p1 = f2bf(fmaxf(acc[2][s], 0.f)) | ((unsigned)f2bf(fmaxf(acc[3][s], 0.f)) << 16);
        p2 = f2bf(fmaxf(acc[4][s], 0.f)) | ((unsigned)f2bf(fmaxf(acc[5][s], 0.f)) << 16);
        p3 = f2bf(fmaxf(acc[6][s], 0.f)) | ((unsigned)f2bf(fmaxf(acc[7][s], 0.f)) << 16);
      }
      *(uint4*)(op + s * 32) = make_uint4(p0, p1, p2, p3);
    }
  }
}

// ---------------- conv2: MFMA, block=(b,oh), waves=(xt2, ch2) ----------------
__global__ __launch_bounds__(256) void k_conv2(
    const u16* __restrict__ z1t, const u16* __restrict__ wf,
    const float* __restrict__ bias, float* __restrict__ z2) {
  int t = threadIdx.x;
  int lane = t & 63, wv = t >> 6;
  int n = lane & 15, q = lane >> 4;
  int oh = blockIdx.x & 31, b = blockIdx.x >> 5;   // grid 2048
  int xt = wv & 1, ch = wv >> 1;
  int xA = xt * 16 + n;
  f32x4 acc[2] = {{0,0,0,0},{0,0,0,0}};
  #pragma unroll
  for (int kh = 0; kh < 3; ++kh) {
    int ih = 2 * oh - 1 + kh;
    bool yok = (unsigned)ih < 63u;
    #pragma unroll
    for (int kw = 0; kw < 3; ++kw) {
      int iw = 2 * xA - 1 + kw;
      bool ok = yok && (iw >= 0);                  // iw==63 reads zero-pad col
      bf16x8 a = {};
      if (ok) a = *(const bf16x8*)(z1t + ((b * 63 + ih) * 64 + iw) * 32 + q * 8);
      int kt = kh * 3 + kw;
      const u16* wb = wf + ((kt << 2) + (ch << 1)) * 512 + lane * 8;
      bf16x8 b0 = *(const bf16x8*)wb;
      bf16x8 b1 = *(const bf16x8*)(wb + 512);
      acc[0] = __builtin_amdgcn_mfma_f32_16x16x32_bf16(a, b0, acc[0], 0, 0, 0);
      acc[1] = __builtin_amdgcn_mfma_f32_16x16x32_bf16(a, b1, acc[1], 0, 0, 0);
    }
  }
  #pragma unroll
  for (int j = 0; j < 2; ++j) {
    int co = ((ch << 1) + j) * 16 + n;
    float bv = bias[co];
    float4 rv = make_float4(fmaxf(acc[j][0] + bv, 0.f), fmaxf(acc[j][1] + bv, 0.f),
                            fmaxf(acc[j][2] + bv, 0.f), fmaxf(acc[j][3] + bv, 0.f));
    *(float4*)(z2 + ((b * 64 + co) * 32 + oh) * 32 + xt * 16 + q * 4) = rv;
  }
}

// ---------------- conv3 (1x1): fp32, 8co x 4px/thread ----------------
__global__ __launch_bounds__(256, 4) void k_conv3(
    const float* __restrict__ in, const float* __restrict__ wp,
    const float* __restrict__ bias, float* __restrict__ out) {
  int t = threadIdx.x;
  int bid = blockIdx.x;              // 512 = 64b x 8cog
  int cog = bid & 7; int b = bid >> 3;
  const float* wcg = wp + cog * 512;
  int px0 = t << 2, co0 = cog * 8;
  float acc[8][4];
  #pragma unroll
  for (int c = 0; c < 8; ++c) {
    float bv = bias[co0 + c];
    #pragma unroll
    for (int s = 0; s < 4; ++s) acc[c][s] = bv;
  }
  const float* ip = in + (b << 16) + px0;
  for (int ci = 0; ci < 64; ++ci) {
    float4 v = *(const float4*)(ip + (ci << 10));
    float4 wa = *(const float4*)(wcg + ci * 8);
    float4 wb = *(const float4*)(wcg + ci * 8 + 4);
    float w8[8] = {wa.x, wa.y, wa.z, wa.w, wb.x, wb.y, wb.z, wb.w};
    #pragma unroll
    for (int c = 0; c < 8; ++c) {
      acc[c][0] = fmaf(v.x, w8[c], acc[c][0]);
      acc[c][1] = fmaf(v.y, w8[c], acc[c][1]);
      acc[c][2] = fmaf(v.z, w8[c], acc[c][2]);
      acc[c][3] = fmaf(v.w, w8[c], acc[c][3]);
    }
  }
  float* op = out + ((b << 6) + co0) * 1024 + px0;
  #pragma unroll
  for (int c = 0; c < 8; ++c)
    *(float4*)(op + (c << 10)) = make_float4(acc[c][0], acc[c][1], acc[c][2], acc[c][3]);
}

// ---------------- VQ partial: 4 K-slices (fp32 exact) ----------------
__global__ __launch_bounds__(256, 4) void k_vqp(
    const float* __restrict__ z3, const float* __restrict__ cb,
    const float* __restrict__ c2v, float2* __restrict__ pb) {
  int t = threadIdx.x;
  int pxb = blockIdx.x & 255;
  int sl  = blockIdx.x >> 8;
  int n = pxb * 256 + t;
  int b = n >> 10, hw = n & 1023;
  const float* zp = z3 + (b << 16) + hw;
  float z[64];
  #pragma unroll
  for (int d = 0; d < 64; ++d) z[d] = zp[d << 10];
  int k0 = sl << 7;
  float best = 3.4e38f; int bi = k0;
  for (int k = k0; k < k0 + 128; ++k) {
    const float4* c4 = (const float4*)(cb + (k << 6));
    float d0 = 0.f, d1 = 0.f, d2 = 0.f, d3 = 0.f;
    #pragma unroll
    for (int i = 0; i < 16; ++i) {
      float4 c = c4[i];
      d0 = fmaf(z[4 * i + 0], c.x, d0);
      d1 = fmaf(z[4 * i + 1], c.y, d1);
      d2 = fmaf(z[4 * i + 2], c.z, d2);
      d3 = fmaf(z[4 * i + 3], c.w, d3);
    }
    float score = c2v[k] - 2.f * ((d0 + d1) + (d2 + d3));
    if (score < best) { best = score; bi = k; }
  }
  pb[(sl << 16) + n] = make_float2(best, __int_as_float(bi));
}

// ---------------- VQ finalize: merge, write e_t bf16, loss ----------------
__global__ __launch_bounds__(256) void k_vqf(
    const float* __restrict__ z3, const float* __restrict__ cb,
    const float2* __restrict__ pb, u16* __restrict__ et,
    float* __restrict__ acc) {
  int n = blockIdx.x * 256 + threadIdx.x;  // 65536
  float best = 3.4e38f; int bi = 0;
  #pragma unroll
  for (int s = 0; s < 4; ++s) {            // ascending slice + strict < = first argmin
    float2 c = pb[(s << 16) + n];
    if (c.x < best) { best = c.x; bi = __float_as_int(c.y); }
  }
  int b = n >> 10, hw = n & 1023;
  const float* zp = z3 + (b << 16) + hw;
  uint2* ep = (uint2*)(et + (n << 6));
  const float4* cq = (const float4*)(cb + (bi << 6));
  float lsum = 0.f;
  #pragma unroll
  for (int i = 0; i < 16; ++i) {
    float4 c = cq[i];
    float zv, df;
    zv = zp[(4*i+0) << 10]; df = c.x - zv; lsum = fmaf(df, df, lsum);
    zv = zp[(4*i+1) << 10]; df = c.y - zv; lsum = fmaf(df, df, lsum);
    zv = zp[(4*i+2) << 10]; df = c.z - zv; lsum = fmaf(df, df, lsum);
    zv = zp[(4*i+3) << 10]; df = c.w - zv; lsum = fmaf(df, df, lsum);
    ep[i] = make_uint2(f2bf(c.x) | ((unsigned)f2bf(c.y) << 16),
                       f2bf(c.z) | ((unsigned)f2bf(c.w) << 16));
  }
  __shared__ float red[256];
  red[threadIdx.x] = lsum; __syncthreads();
  #pragma unroll
  for (int s = 128; s > 0; s >>= 1) {
    if (threadIdx.x < s) red[threadIdx.x] += red[threadIdx.x + s];
    __syncthreads();
  }
  if (threadIdx.x == 0) atomicAdd(acc + 0, red[0]);
}

// ---------------- convT1: MFMA both-parity waves, waves=(cog2, xt2) ----------------
__global__ __launch_bounds__(256) void k_convT1(
    const u16* __restrict__ et, const u16* __restrict__ wf,
    const float* __restrict__ bias, u16* __restrict__ h1t) {
  int t = threadIdx.x;
  int lane = t & 63, wv = t >> 6;
  int n = lane & 15, q = lane >> 4;
  int oh = blockIdx.x & 63, b = blockIdx.x >> 6;   // grid 4096
  int ph = oh & 1, y = oh >> 1;
  int cog = wv >> 1, xt = wv & 1;
  int m = xt * 16 + n;                             // input pixel base (dx=0)
  f32x4 acc[2][2] = {};                            // [nf-local][pw]
  int khs[2], dys[2], nh;
  if (ph) { nh = 2; khs[0] = 0; dys[0] = 1; khs[1] = 2; dys[1] = 0; }
  else    { nh = 1; khs[0] = 1; dys[0] = 0; }
  for (int a_ = 0; a_ < nh; ++a_) {
    int yy = y + dys[a_];
    bool yok = yy < 32;
    const u16* rowp = et + (((b * 32 + yy) * 32) << 6) + q * 8;
    bf16x8 A0s0 = {}, A0s1 = {}, A1s0 = {}, A1s1 = {};
    if (yok) {
      const u16* p0 = rowp + (m << 6);
      A0s0 = *(const bf16x8*)p0; A0s1 = *(const bf16x8*)(p0 + 32);
      if (m + 1 < 32) {
        const u16* p1 = rowp + ((m + 1) << 6);
        A1s0 = *(const bf16x8*)p1; A1s1 = *(const bf16x8*)(p1 + 32);
      }
    }
    int kh = khs[a_];
    #pragma unroll
    for (int kw = 0; kw < 3; ++kw) {
      int kt = kh * 3 + kw;
      int pwi = (kw == 1) ? 0 : 1;
      bf16x8 As0 = (kw == 0) ? A1s0 : A0s0;
      bf16x8 As1 = (kw == 0) ? A1s1 : A0s1;
      const u16* wb = wf + (kt << 12) + lane * 8;  // kt*8*512
      #pragma unroll
      for (int j = 0; j < 2; ++j) {
        int nf = cog * 2 + j;
        bf16x8 b0 = *(const bf16x8*)(wb + nf * 512);
        bf16x8 b1 = *(const bf16x8*)(wb + (4 + nf) * 512);
        acc[j][pwi] = __builtin_amdgcn_mfma_f32_16x16x32_bf16(As0, b0, acc[j][pwi], 0, 0, 0);
        acc[j][pwi] = __builtin_amdgcn_mfma_f32_16x16x32_bf16(As1, b1, acc[j][pwi], 0, 0, 0);
      }
    }
  }
  u16* op = h1t + (((b * 64 + oh) * 64) << 6);
  #pragma unroll
  for (int j = 0; j < 2; ++j) {
    int co = (cog * 2 + j) * 16 + n;
    float bv = bias[co];
    #pragma unroll
    for (int pw = 0; pw < 2; ++pw)
      #pragma unroll
      for (int r = 0; r < 4; ++r) {
        int ow = 2 * (xt * 16 + q * 4 + r) + pw;
        op[(ow << 6) + co] = f2bf(fmaxf(acc[j][pw][r] + bv, 0.f));
      }
  }
}

// ---------------- convT2: MFMA both-parity waves, waves=xt4 ----------------
__global__ __launch_bounds__(256) void k_convT2(
    const u16* __restrict__ h1t, const u16* __restrict__ wf,
    const float* __restrict__ bias, u16* __restrict__ h2t) {
  int t = threadIdx.x;
  int lane = t & 63, wv = t >> 6;                  // 4 waves = xt
  int n = lane & 15, q = lane >> 4;
  int oh = blockIdx.x & 127, b = blockIdx.x >> 7;  // grid 8192
  int ph = oh & 1, y = oh >> 1;
  int xt = wv;
  int m = xt * 16 + n;                             // input pixel base
  f32x4 acc[2][2] = {};                            // [nf][pw]
  int khs[2], dys[2], nh;
  if (ph) { nh = 2; khs[0] = 0; dys[0] = 1; khs[1] = 2; dys[1] = 0; }
  else    { nh = 1; khs[0] = 1; dys[0] = 0; }
  for (int a_ = 0; a_ < nh; ++a_) {
    int yy = y + dys[a_];
    bool yok = yy < 64;
    const u16* rowp = h1t + (((b * 64 + yy) * 64) << 6) + q * 8;
    bf16x8 A0s0 = {}, A0s1 = {}, A1s0 = {}, A1s1 = {};
    if (yok) {
      const u16* p0 = rowp + (m << 6);
      A0s0 = *(const bf16x8*)p0; A0s1 = *(const bf16x8*)(p0 + 32);
      if (m + 1 < 64) {
        const u16* p1 = rowp + ((m + 1) << 6);
        A1s0 = *(const bf16x8*)p1; A1s1 = *(const bf16x8*)(p1 + 32);
      }
    }
    int kh = khs[a_];
    #pragma unroll
    for (int kw = 0; kw < 3; ++kw) {
      int kt = kh * 3 + kw;
      int pwi = (kw == 1) ? 0 : 1;
      bf16x8 As0 = (kw == 0) ? A1s0 : A0s0;
      bf16x8 As1 = (kw == 0) ? A1s1 : A0s1;
      const u16* wb = wf + (kt << 11) + lane * 8;  // kt*4*512
      #pragma unroll
      for (int nf = 0; nf < 2; ++nf) {
        bf16x8 b0 = *(const bf16x8*)(wb + nf * 512);
        bf16x8 b1 = *(const bf16x8*)(wb + (2 + nf) * 512);
        acc[nf][pwi] = __builtin_amdgcn_mfma_f32_16x16x32_bf16(As0, b0, acc[nf][pwi], 0, 0, 0);
        acc[nf][pwi] = __builtin_amdgcn_mfma_f32_16x16x32_bf16(As1, b1, acc[nf][pwi], 0, 0, 0);
      }
    }
  }
  u16* op = h2t + (((b * 128 + oh) * 128) << 5);
  #pragma unroll
  for (int nf = 0; nf < 2; ++nf) {
    int co = nf * 16 + n;
    float bv = bias[co];
    #pragma unroll
    for (int pw = 0; pw < 2; ++pw)
      #pragma unroll
      for (int r = 0; r < 4; ++r) {
        int ow = 2 * (xt * 16 + q * 4 + r) + pw;
        op[(ow << 5) + co] = f2bf(fmaxf(acc[nf][pw][r] + bv, 0.f));
      }
  }
}

// ---------------- convT3 + recon loss: pixel-major bf16 input ----------------
__global__ __launch_bounds__(256, 4) void k_convT3(
    const u16* __restrict__ h2t,   // [64][128][128][32] bf16
    const float* __restrict__ wt,  // wt3n [kh2][kw2][ci32][4]
    const float* __restrict__ bias, const float* __restrict__ x,
    float* __restrict__ xr, float* __restrict__ acc) {
  int t = threadIdx.x;
  int idx = blockIdx.x * 256 + t;    // 128000 exact
  int owg = idx & 15; int t2 = idx >> 4;
  int oh = t2 % 125; int b = t2 / 125;
  int ow0 = owg * 8;
  float a[3][8];
  #pragma unroll
  for (int s = 0; s < 8; ++s) { a[0][s] = bias[0]; a[1][s] = bias[1]; a[2][s] = bias[2]; }
  #pragma unroll
  for (int r2 = 0; r2 < 2; ++r2) {
    int inrow = oh + 1 + r2;           // r2=0 -> kh=1 ; r2=1 -> kh=0
    int kh = 1 - r2;
    const u16* rp = h2t + (((b * 128 + inrow) * 128) + ow0) * 32;
    const float* wb = wt + kh * 256;   // [kw][ci32][4]
    #pragma unroll
    for (int c = 1; c <= 9; ++c) {     // input col ow0+c (col<=129 bleed: masked out)
      float f[32];
      #pragma unroll
      for (int g = 0; g < 4; ++g) {
        uint4 u = *((const uint4*)(rp + c * 32) + g);
        f[g*8+0] = __uint_as_float(u.x << 16); f[g*8+1] = __uint_as_float(u.x & 0xffff0000u);
        f[g*8+2] = __uint_as_float(u.y << 16); f[g*8+3] = __uint_as_float(u.y & 0xffff0000u);
        f[g*8+4] = __uint_as_float(u.z << 16); f[g*8+5] = __uint_as_float(u.z & 0xffff0000u);
        f[g*8+6] = __uint_as_float(u.w << 16); f[g*8+7] = __uint_as_float(u.w & 0xffff0000u);
      }
      if (c <= 8) {                    // kw=1 -> s = c-1
        const float* wk = wb + 128;
        int s = c - 1;
        #pragma unroll
        for (int ci = 0; ci < 32; ++ci) {
          float fv = f[ci];
          a[0][s] = fmaf(fv, wk[ci*4+0], a[0][s]);
          a[1][s] = fmaf(fv, wk[ci*4+1], a[1][s]);
          a[2][s] = fmaf(fv, wk[ci*4+2], a[2][s]);
        }
      }
      if (c >= 2) {                    // kw=0 -> s = c-2
        const float* wk = wb;
        int s = c - 2;
        #pragma unroll
        for (int ci = 0; ci < 32; ++ci) {
          float fv = f[ci];
          a[0][s] = fmaf(fv, wk[ci*4+0], a[0][s]);
          a[1][s] = fmaf(fv, wk[ci*4+1], a[1][s]);
          a[2][s] = fmaf(fv, wk[ci*4+2], a[2][s]);
        }
      }
    }
  }
  int o = b * 46875 + oh * 125 + ow0;
  float lsum = 0.f;
  #pragma unroll
  for (int s = 0; s < 8; ++s) {
    if (ow0 + s < 125) {
      #pragma unroll
      for (int c = 0; c < 3; ++c) {
        float val = a[c][s];
        xr[o + s + c * 15625] = val;
        float d = val - x[o + s + c * 15625];
        lsum = fmaf(d, d, lsum);
      }
    }
  }
  __shared__ float red[256];
  red[t] = lsum; __syncthreads();
  #pragma unroll
  for (int s = 128; s > 0; s >>= 1) {
    if (t < s) red[t] += red[t + s];
    __syncthreads();
  }
  if (t == 0) atomicAdd(acc + 1, red[0]);
}

// ---------------- finalize ----------------
__global__ void k_fin(const float* __restrict__ acc, float* __restrict__ out) {
  if (threadIdx.x == 0 && blockIdx.x == 0) {
    float eq  = 1.25f * acc[0] / 4194304.0f;
    float rec = acc[1];
    out[0] = eq + rec;
    out[1] = eq;
    out[2] = rec;
  }
}

extern "C" void kernel_launch(void* const* d_in, const int* in_sizes, int n_in,
                              void* d_out, int out_size, void* d_ws, size_t ws_size,
                              hipStream_t stream) {
  (void)in_sizes; (void)n_in; (void)out_size; (void)ws_size;
  const float* x   = (const float*)d_in[0];
  const float* ew1 = (const float*)d_in[1];
  const float* eb1 = (const float*)d_in[2];
  const float* ew2 = (const float*)d_in[3];
  const float* eb2 = (const float*)d_in[4];
  const float* ew3 = (const float*)d_in[5];
  const float* eb3 = (const float*)d_in[6];
  const float* cb  = (const float*)d_in[7];
  const float* dw1 = (const float*)d_in[8];
  const float* db1 = (const float*)d_in[9];
  const float* dw2 = (const float*)d_in[10];
  const float* db2 = (const float*)d_in[11];
  const float* dw3 = (const float*)d_in[12];
  const float* db3 = (const float*)d_in[13];
  float* out = (float*)d_out;
  char*  ws  = (char*)d_ws;

  float*  acc  = (float*)(ws + 0);
  float*  c2   = (float*)(ws + 256);
  float*  wc1p = (float*)(ws + 4096);
  float*  wc3p = (float*)(ws + 8192);
  float*  wt3n = (float*)(ws + 24576);
  u16*    w2f  = (u16*)  (ws + 32768);
  u16*    wt1f = (u16*)  (ws + 69632);
  u16*    wt2f = (u16*)  (ws + 143360);
  // Lifetimes: z1t dead after conv2; z2 after conv3; z3/pb after vqf;
  // e_t after convT1; h1t (over dead z1t/z2) after convT2; h2t to convT3.
  u16*    z1t  = (u16*)  (ws + 1048576);  // 16515072 B
  float*  z2   = (float*)(ws + 18874368); // 16777216 B
  float*  z3   = (float*)(ws + 35651584); // 16777216 B
  float2* pb   = (float2*)(ws + 52428800);//  2097152 B
  u16*    et   = (u16*)  (ws + 54525952); //  8388608 B
  u16*    h1t  = (u16*)  (ws + 1048576);  // 33030144 B
  u16*    h2t  = (u16*)  (ws + 67108864); // 67108864 B -> ends 134217728

  hipMemsetAsync(acc, 0, 64, stream);
  k_prep  <<<312,  256, 0, stream>>>(ew1, ew2, ew3, dw1, dw2, dw3, cb,
                                     wc1p, wc3p, wt3n, c2, w2f, wt1f, wt2f);
  k_conv1 <<<1024, 256, 0, stream>>>(x, wc1p, eb1, z1t);
  k_conv2 <<<2048, 256, 0, stream>>>(z1t, w2f, eb2, z2);
  k_conv3 <<<512,  256, 0, stream>>>(z2, wc3p, eb3, z3);
  k_vqp   <<<1024, 256, 0, stream>>>(z3, cb, c2, pb);
  k_vqf   <<<256,  256, 0, stream>>>(z3, cb, pb, et, acc);
  k_convT1<<<4096, 256, 0, stream>>>(et, wt1f, db1, h1t);
  k_convT2<<<8192, 256, 0, stream>>>(h1t, wt2f, db2, h2t);
  k_convT3<<<500,  256, 0, stream>>>(h2t, wt3n, db3, x, out + 3, acc);
  k_fin   <<<1,    64,  0, stream>>>(acc, out);
}